// Round 13
// baseline (18643.854 us; speedup 1.0000x reference)
//
#include <hip/hip_runtime.h>
#include <limits.h>

#define CDIM 256
#define KDIM 8192
#define NROWS 32768
#define THW 8192
#define BNQ 64
#define TAU 2.0e-4f

typedef __attribute__((ext_vector_type(8))) short short8v;   // 8 bf16 (4 VGPR)
typedef __attribute__((ext_vector_type(4))) float f32x4;
typedef __attribute__((ext_vector_type(4))) unsigned short u16x4;

// ws layout (bytes):
//   [0,       4194304)  W1[k][c] bf16 hi split of w
//   [4194304, 8388608)  W2[k][c] bf16 lo split
//   [8388608, 8519680)  A[n]  np-exact (32768 f32)
//   [8519680, 8552448)  Cq[k] np-exact (8192 f32)
//   [8552448, 8683520)  flag[n] (32768 i32)  -- 1 = needs np-exact resolve
//   [8683520, 8685568)  loss partials (512 f32)
// Every region fully rewritten every call; no atomics anywhere.

__device__ __forceinline__ float sq_rn(float a) { return __fmul_rn(a, a); }
__device__ __forceinline__ unsigned short bf16rn(float x) {
    unsigned u = __float_as_uint(x);
    return (unsigned short)((u + 0x7FFFu + ((u >> 16) & 1u)) >> 16);
}
__device__ __forceinline__ float bf16tof(unsigned short h) {
    return __uint_as_float(((unsigned)h) << 16);
}

// numpy pairwise sum of 128 fp32 squares, AVX512 model (verified round 3).
__device__ float pairwise128_sq(const float* __restrict__ p, int stride) {
    float s[16];
#pragma unroll
    for (int l = 0; l < 16; ++l) {
        const float a0 = sq_rn(p[(l)*stride]);
        const float a1 = sq_rn(p[(16 + l) * stride]);
        const float a2 = sq_rn(p[(32 + l) * stride]);
        const float a3 = sq_rn(p[(48 + l) * stride]);
        const float a4 = sq_rn(p[(64 + l) * stride]);
        const float a5 = sq_rn(p[(80 + l) * stride]);
        const float a6 = sq_rn(p[(96 + l) * stride]);
        const float a7 = sq_rn(p[(112 + l) * stride]);
        s[l] = __fadd_rn(__fadd_rn(__fadd_rn(a0, a1), __fadd_rn(a2, a3)),
                         __fadd_rn(__fadd_rn(a4, a5), __fadd_rn(a6, a7)));
    }
    const float u0 = __fadd_rn(__fadd_rn(s[0], s[8]),  __fadd_rn(s[4], s[12]));
    const float u1 = __fadd_rn(__fadd_rn(s[1], s[9]),  __fadd_rn(s[5], s[13]));
    const float u2 = __fadd_rn(__fadd_rn(s[2], s[10]), __fadd_rn(s[6], s[14]));
    const float u3 = __fadd_rn(__fadd_rn(s[3], s[11]), __fadd_rn(s[7], s[15]));
    return __fadd_rn(__fadd_rn(u0, u2), __fadd_rn(u1, u3));
}

__global__ __launch_bounds__(256) void k_A(const float* __restrict__ z,
                                           float* __restrict__ A) {
    const int n = blockIdx.x * 256 + threadIdx.x;
    const float* zp = z + (size_t)(n >> 13) * (CDIM * THW) + (n & (THW - 1));
    const float b0 = pairwise128_sq(zp, THW);
    const float b1 = pairwise128_sq(zp + (size_t)128 * THW, THW);
    A[n] = __fadd_rn(b0, b1);
}

__global__ __launch_bounds__(256) void k_C(const float* __restrict__ w,
                                           float* __restrict__ Cq) {
    const int k = blockIdx.x * 256 + threadIdx.x;
    const float* wp = w + (size_t)k * CDIM;
    Cq[k] = __fadd_rn(pairwise128_sq(wp, 1), pairwise128_sq(wp + 128, 1));
}

// Split w -> bf16 hi/lo, row-major [k][c].
__global__ __launch_bounds__(256) void k_split(const float* __restrict__ w,
                                               unsigned short* __restrict__ W1,
                                               unsigned short* __restrict__ W2) {
    const int i = blockIdx.x * 256 + threadIdx.x;
    float4 v = *reinterpret_cast<const float4*>(w + (size_t)i * 4);
    const float x[4] = {v.x, v.y, v.z, v.w};
    u16x4 h, lo;
#pragma unroll
    for (int q = 0; q < 4; ++q) {
        const unsigned short hh = bf16rn(x[q]);
        h[q] = hh;
        lo[q] = bf16rn(x[q] - bf16tof(hh));
    }
    *reinterpret_cast<u16x4*>(W1 + (size_t)i * 4) = h;
    *reinterpret_cast<u16x4*>(W2 + (size_t)i * 4) = lo;
}

// MFMA split-bf16 filter with per-row register top-2 (m1, i1, m2) of
// df = RN(RN(A - 2*dot) + Cq), |df - d_np| <= e ~ 6.2e-5. flag[n] = 1 iff
// m2 - m1 <= TAU (2e-4 >= 2e): uncertified -> np-exact resolve. Unflagged:
// df-argmin == np-argmin, certified. (df numerics validated end-to-end in
// rounds 10/11: first-call absmax 4.8e-7 over all rows.) No atomics.
__global__ __launch_bounds__(256, 2) void k_filter(
    const float* __restrict__ z,
    const unsigned short* __restrict__ W1, const unsigned short* __restrict__ W2,
    const float* __restrict__ A, const float* __restrict__ Cq,
    float* __restrict__ idx_f, int* __restrict__ flag)
{
    __shared__ unsigned short Z1t[64 * 256];  // 32 KB, [n][c] swizzled bf16 hi
    __shared__ unsigned short Z2t[64 * 256];  // 32 KB, lo
    __shared__ float wm1[4][64];
    __shared__ int   wi1[4][64];
    __shared__ float wm2[4][64];

    const int t = threadIdx.x;
    const int blk = blockIdx.x;
    const int b = (blk * 64) >> 13;
    const int s0 = (blk * 64) & (THW - 1);
    const float* zb = z + (size_t)b * (CDIM * THW) + s0;

    {   // stage + split z tile (coalesced reads, swizzled LDS writes)
        const int lane = t & 15;
        const int c0 = t >> 4;
#pragma unroll
        for (int it = 0; it < 16; ++it) {
            const int c = c0 + it * 16;
            float4 v = *reinterpret_cast<const float4*>(zb + (size_t)c * THW + lane * 4);
            const float vv[4] = {v.x, v.y, v.z, v.w};
#pragma unroll
            for (int q = 0; q < 4; ++q) {
                const int n = lane * 4 + q;
                const unsigned short h = bf16rn(vv[q]);
                const unsigned short l2 = bf16rn(vv[q] - bf16tof(h));
                const int off = n * 512 + ((c * 2) ^ ((n & 7) << 4));
                *(unsigned short*)((char*)Z1t + off) = h;
                *(unsigned short*)((char*)Z2t + off) = l2;
            }
        }
    }
    __syncthreads();

    const int l = t & 63;
    const int wv = t >> 6;
    const int l15 = l & 15;
    const int lg = l >> 4;
    const int stripe = wv * 2048;

    float4 Av[4];
#pragma unroll
    for (int rt = 0; rt < 4; ++rt)
        Av[rt] = *reinterpret_cast<const float4*>(A + blk * 64 + rt * 16 + lg * 4);

    float b1r[4][4], b2r[4][4];
    int k1r[4][4];
#pragma unroll
    for (int rt = 0; rt < 4; ++rt)
#pragma unroll
        for (int i = 0; i < 4; ++i) {
            b1r[rt][i] = 3.0e38f; b2r[rt][i] = 3.0e38f; k1r[rt][i] = INT_MAX;
        }

    for (int st = 0; st < 32; ++st) {
        const int kb = stripe + st * 64;
        f32x4 acc[4][4];
#pragma unroll
        for (int rt = 0; rt < 4; ++rt)
#pragma unroll
            for (int ct = 0; ct < 4; ++ct)
                acc[rt][ct] = (f32x4){0.f, 0.f, 0.f, 0.f};

        float cqv[4];
#pragma unroll
        for (int ct = 0; ct < 4; ++ct) cqv[ct] = Cq[kb + ct * 16 + l15];

#pragma unroll
        for (int ks = 0; ks < 8; ++ks) {
            const int cb = ks * 32 + lg * 8;
            short8v a1[4], a2[4], bb1[4], bb2[4];
#pragma unroll
            for (int rt = 0; rt < 4; ++rt) {
                const int n = rt * 16 + l15;
                const int off = n * 512 + ((cb * 2) ^ ((n & 7) << 4));
                a1[rt] = *(const short8v*)((const char*)Z1t + off);
                a2[rt] = *(const short8v*)((const char*)Z2t + off);
            }
#pragma unroll
            for (int ct = 0; ct < 4; ++ct) {
                const size_t wo = (size_t)(kb + ct * 16 + l15) * CDIM + cb;
                bb1[ct] = *reinterpret_cast<const short8v*>(W1 + wo);
                bb2[ct] = *reinterpret_cast<const short8v*>(W2 + wo);
            }
#pragma unroll
            for (int rt = 0; rt < 4; ++rt)
#pragma unroll
                for (int ct = 0; ct < 4; ++ct) {
                    acc[rt][ct] = __builtin_amdgcn_mfma_f32_16x16x32_bf16(a1[rt], bb1[ct], acc[rt][ct], 0, 0, 0);
                    acc[rt][ct] = __builtin_amdgcn_mfma_f32_16x16x32_bf16(a1[rt], bb2[ct], acc[rt][ct], 0, 0, 0);
                    acc[rt][ct] = __builtin_amdgcn_mfma_f32_16x16x32_bf16(a2[rt], bb1[ct], acc[rt][ct], 0, 0, 0);
                }
        }

        // per-lane running top-2 per row; C-layout row = rt*16+lg*4+i,
        // col code = kb + ct*16 + l15; ct ascending = code ascending.
#pragma unroll
        for (int rt = 0; rt < 4; ++rt)
#pragma unroll
            for (int i = 0; i < 4; ++i) {
                const float Ai = ((const float*)&Av[rt])[i];
#pragma unroll
                for (int ct = 0; ct < 4; ++ct) {
                    const float d_ = __fadd_rn(__fadd_rn(Ai, -2.0f * acc[rt][ct][i]), cqv[ct]);
                    const int kg = kb + ct * 16 + l15;
                    if (d_ < b1r[rt][i]) {
                        b2r[rt][i] = b1r[rt][i]; b1r[rt][i] = d_; k1r[rt][i] = kg;
                    } else {
                        b2r[rt][i] = fminf(b2r[rt][i], d_);
                    }
                }
            }
    }

    // top-2 merge across the 16 lanes of each lg group (ties -> lower k)
#pragma unroll
    for (int mm = 1; mm < 16; mm <<= 1) {
#pragma unroll
        for (int rt = 0; rt < 4; ++rt)
#pragma unroll
            for (int i = 0; i < 4; ++i) {
                const float ob = __shfl_xor(b1r[rt][i], mm, 64);
                const int oi = __shfl_xor(k1r[rt][i], mm, 64);
                const float ob2 = __shfl_xor(b2r[rt][i], mm, 64);
                if (ob < b1r[rt][i] || (ob == b1r[rt][i] && oi < k1r[rt][i])) {
                    b2r[rt][i] = fminf(b1r[rt][i], ob2);
                    b1r[rt][i] = ob; k1r[rt][i] = oi;
                } else {
                    b2r[rt][i] = fminf(b2r[rt][i], ob);
                }
            }
    }
    if (l15 == 0) {
#pragma unroll
        for (int rt = 0; rt < 4; ++rt)
#pragma unroll
            for (int i = 0; i < 4; ++i) {
                const int row = rt * 16 + lg * 4 + i;
                wm1[wv][row] = b1r[rt][i];
                wi1[wv][row] = k1r[rt][i];
                wm2[wv][row] = b2r[rt][i];
            }
    }
    __syncthreads();

    if (t < 64) {
        float m1 = 3.0e38f, m2 = 3.0e38f;
        int i1 = INT_MAX;
#pragma unroll
        for (int v = 0; v < 4; ++v) {
            const float a1 = wm1[v][t], a2 = wm2[v][t];
            const int ai = wi1[v][t];
            if (a1 < m1 || (a1 == m1 && ai < i1)) {
                m2 = fminf(m1, a2); m1 = a1; i1 = ai;
            } else {
                m2 = fminf(m2, a1);
            }
        }
        const int n = blk * 64 + t;
        idx_f[n] = (float)i1;
        flag[n] = (m2 - m1 <= TAU) ? 1 : 0;   // plain store, deterministic
    }
}

// np-exact full scan for flagged rows: block owns rows [blk*16, blk*16+16);
// 4 interleaved single-ascending-c fmaf chains per thread; d = RN(RN(A-2M)+Cq);
// argmin ties -> lowest k (np.argmin). No atomics, static ownership.
__global__ __launch_bounds__(256) void k_resolve(
    const float* __restrict__ z, const float* __restrict__ w,
    const float* __restrict__ A, const float* __restrict__ Cq,
    const int* __restrict__ flag, float* __restrict__ idx_f)
{
    __shared__ __align__(16) float zrow[CDIM];
    __shared__ float rmv[256];
    __shared__ int rki[256];
    const int t = threadIdx.x;

    for (int i = 0; i < 16; ++i) {
        const int n = blockIdx.x * 16 + i;
        if (!flag[n]) continue;           // uniform read -> uniform branch
        const int b = n >> 13;
        const int s = n & (THW - 1);
        __syncthreads();                  // zrow/rmv from prev iter consumed
        zrow[t] = z[(size_t)b * (CDIM * THW) + (size_t)t * THW + s];
        __syncthreads();

        const float An = A[n];
        float bd = 3.0e38f;
        int bk = INT_MAX;
#pragma unroll 1
        for (int base = 0; base < KDIM; base += 1024) {
            const int k0 = base + t;
            const float4* W0 = (const float4*)(w + (size_t)k0 * CDIM);
            const float4* W1p = (const float4*)(w + (size_t)(k0 + 256) * CDIM);
            const float4* W2p = (const float4*)(w + (size_t)(k0 + 512) * CDIM);
            const float4* W3p = (const float4*)(w + (size_t)(k0 + 768) * CDIM);
            float m0 = 0.f, m1 = 0.f, m2 = 0.f, m3 = 0.f;
#pragma unroll 8
            for (int c4 = 0; c4 < CDIM / 4; ++c4) {
                const float4 zv = *reinterpret_cast<const float4*>(&zrow[c4 * 4]);
                const float4 v0 = W0[c4], v1 = W1p[c4], v2 = W2p[c4], v3 = W3p[c4];
                m0 = fmaf(zv.x, v0.x, m0); m0 = fmaf(zv.y, v0.y, m0);
                m0 = fmaf(zv.z, v0.z, m0); m0 = fmaf(zv.w, v0.w, m0);
                m1 = fmaf(zv.x, v1.x, m1); m1 = fmaf(zv.y, v1.y, m1);
                m1 = fmaf(zv.z, v1.z, m1); m1 = fmaf(zv.w, v1.w, m1);
                m2 = fmaf(zv.x, v2.x, m2); m2 = fmaf(zv.y, v2.y, m2);
                m2 = fmaf(zv.z, v2.z, m2); m2 = fmaf(zv.w, v2.w, m2);
                m3 = fmaf(zv.x, v3.x, m3); m3 = fmaf(zv.y, v3.y, m3);
                m3 = fmaf(zv.z, v3.z, m3); m3 = fmaf(zv.w, v3.w, m3);
            }
            const float d0 = __fadd_rn(__fadd_rn(An, -2.0f * m0), Cq[k0]);
            const float d1 = __fadd_rn(__fadd_rn(An, -2.0f * m1), Cq[k0 + 256]);
            const float d2 = __fadd_rn(__fadd_rn(An, -2.0f * m2), Cq[k0 + 512]);
            const float d3 = __fadd_rn(__fadd_rn(An, -2.0f * m3), Cq[k0 + 768]);
            // ascending k within thread: strict < keeps lowest on ties
            if (d0 < bd) { bd = d0; bk = k0; }
            if (d1 < bd) { bd = d1; bk = k0 + 256; }
            if (d2 < bd) { bd = d2; bk = k0 + 512; }
            if (d3 < bd) { bd = d3; bk = k0 + 768; }
        }
        rmv[t] = bd; rki[t] = bk;
        __syncthreads();
        for (int mm = 128; mm > 0; mm >>= 1) {
            if (t < mm) {
                if (rmv[t + mm] < rmv[t] ||
                    (rmv[t + mm] == rmv[t] && rki[t + mm] < rki[t])) {
                    rmv[t] = rmv[t + mm]; rki[t] = rki[t + mm];
                }
            }
            __syncthreads();
        }
        if (t == 0) idx_f[n] = (float)rki[0];
    }
}

// Gather z_q = w[idx], transpose to [B,C,T,H,W], accumulate sum((z_q - z)^2).
__global__ __launch_bounds__(256, 2) void k_out(
    const float* __restrict__ w, const float* __restrict__ z,
    const float* __restrict__ idx_f, float* __restrict__ out0,
    float* __restrict__ partial)
{
    __shared__ float q[CDIM][BNQ + 1];
    __shared__ int si[BNQ];
    __shared__ float red[256];

    const int t = threadIdx.x;
    const int blk = blockIdx.x;
    const int n0 = blk * BNQ;
    const int b = n0 >> 13;
    const int s0 = n0 & (THW - 1);

    if (t < BNQ) si[t] = (int)idx_f[n0 + t];
    __syncthreads();

    {
        const int c = t;
#pragma unroll 4
        for (int i = 0; i < BNQ; ++i)
            q[c][i] = w[(size_t)si[i] * CDIM + c];
    }
    __syncthreads();

    const int sl = t & 63;
    const int cb = t >> 6;
    float lacc = 0.f;
    const size_t base = (size_t)b * (CDIM * THW) + s0 + sl;
#pragma unroll 4
    for (int j = 0; j < 64; ++j) {
        const int c = cb * 64 + j;
        const float qv = q[c][sl];
        const size_t a = base + (size_t)c * THW;
        const float zv = z[a];
        out0[a] = qv;
        const float d = qv - zv;
        lacc = fmaf(d, d, lacc);
    }
    red[t] = lacc;
    __syncthreads();
    for (int mm = 128; mm > 0; mm >>= 1) {
        if (t < mm) red[t] += red[t + mm];
        __syncthreads();
    }
    if (t == 0) partial[blk] = red[0];
}

__global__ __launch_bounds__(256) void k_loss(const float* __restrict__ partial,
                                              float* __restrict__ out_loss) {
    __shared__ double red[256];
    const int t = threadIdx.x;
    double a = 0.0;
    for (int i = t; i < NROWS / BNQ; i += 256) a += (double)partial[i];
    red[t] = a;
    __syncthreads();
    for (int mm = 128; mm > 0; mm >>= 1) {
        if (t < mm) red[t] += red[t + mm];
        __syncthreads();
    }
    if (t == 0) out_loss[0] = (float)(1.25 * red[0] / 8388608.0);
}

extern "C" void kernel_launch(void* const* d_in, const int* in_sizes, int n_in,
                              void* d_out, int out_size, void* d_ws, size_t ws_size,
                              hipStream_t stream) {
    const float* z = (const float*)d_in[0];
    const float* w = (const float*)d_in[1];
    float* out = (float*)d_out;

    char* ws = (char*)d_ws;
    unsigned short* W1 = (unsigned short*)ws;                // 4 MB
    unsigned short* W2 = (unsigned short*)(ws + 4194304);    // 4 MB
    float* A = (float*)(ws + 8388608);                       // 128 KB
    float* Cq = (float*)(ws + 8519680);                      // 32 KB
    int* flag = (int*)(ws + 8552448);                        // 128 KB
    float* partial = (float*)(ws + 8683520);                 // 2 KB

    float* out_zq = out;                 // [B,C,T,H,W] = 8388608
    float* out_loss = out + 8388608;     // scalar
    float* out_idx = out + 8388609;      // [B,T,H,W] = 32768, as float

    k_split<<<KDIM * CDIM / 4 / 256, 256, 0, stream>>>(w, W1, W2);
    k_A<<<NROWS / 256, 256, 0, stream>>>(z, A);
    k_C<<<KDIM / 256, 256, 0, stream>>>(w, Cq);
    k_filter<<<NROWS / 64, 256, 0, stream>>>(z, W1, W2, A, Cq, out_idx, flag);
    k_resolve<<<NROWS / 16, 256, 0, stream>>>(z, w, A, Cq, flag, out_idx);
    k_out<<<NROWS / BNQ, 256, 0, stream>>>(w, z, out_idx, out_zq, partial);
    k_loss<<<1, 256, 0, stream>>>(partial, out_loss);
}

// Round 14
// 1844.514 us; speedup vs baseline: 10.1077x; 10.1077x over previous
//
#include <hip/hip_runtime.h>
#include <limits.h>

#define CDIM 256
#define KDIM 8192
#define NROWS 32768
#define THW 8192
#define BNQ 64
#define BNR 32       // resolve rows per block
#define WSIG 8.0e-5f // certified sigma window: 2*r_max(6.1e-5) + 2*delta' + cushion

typedef __attribute__((ext_vector_type(8))) short short8v;   // 8 bf16 (4 VGPR)
typedef __attribute__((ext_vector_type(4))) float f32x4;
typedef __attribute__((ext_vector_type(4))) unsigned short u16x4;

// ws layout (bytes):
//   [0,       8388608)  W1 (4MB) + W2 (4MB) bf16 splits; REUSED as wT[c][k]
//                       (f32, 8MB) after k_filter (k_T runs post-filter)
//   [8388608, 8519680)  A[n]  np-exact (32768 f32)
//   [8519680, 8552448)  Cq[k] np-exact (8192 f32)
//   [8552448, 8683520)  flag[n] (32768 i32)
//   [8683520, 8685568)  cnt64[512] per-filter-block flag count
//   [8685568, 8687616)  off[512] exclusive prefix
//   [8687616, 8687680)  nf (1 i32)
//   [8687680, 8818752)  wlist (32768 i32) compacted flagged rows
//   [8818752, 8820800)  loss partials (512 f32)
// All regions rewritten every call; zero atomics in the pipeline.

__device__ __forceinline__ float sq_rn(float a) { return __fmul_rn(a, a); }
__device__ __forceinline__ unsigned short bf16rn(float x) {
    unsigned u = __float_as_uint(x);
    return (unsigned short)((u + 0x7FFFu + ((u >> 16) & 1u)) >> 16);
}
__device__ __forceinline__ float bf16tof(unsigned short h) {
    return __uint_as_float(((unsigned)h) << 16);
}

// numpy pairwise sum of 128 fp32 squares, AVX512 model (verified round 3).
__device__ float pairwise128_sq(const float* __restrict__ p, int stride) {
    float s[16];
#pragma unroll
    for (int l = 0; l < 16; ++l) {
        const float a0 = sq_rn(p[(l)*stride]);
        const float a1 = sq_rn(p[(16 + l) * stride]);
        const float a2 = sq_rn(p[(32 + l) * stride]);
        const float a3 = sq_rn(p[(48 + l) * stride]);
        const float a4 = sq_rn(p[(64 + l) * stride]);
        const float a5 = sq_rn(p[(80 + l) * stride]);
        const float a6 = sq_rn(p[(96 + l) * stride]);
        const float a7 = sq_rn(p[(112 + l) * stride]);
        s[l] = __fadd_rn(__fadd_rn(__fadd_rn(a0, a1), __fadd_rn(a2, a3)),
                         __fadd_rn(__fadd_rn(a4, a5), __fadd_rn(a6, a7)));
    }
    const float u0 = __fadd_rn(__fadd_rn(s[0], s[8]),  __fadd_rn(s[4], s[12]));
    const float u1 = __fadd_rn(__fadd_rn(s[1], s[9]),  __fadd_rn(s[5], s[13]));
    const float u2 = __fadd_rn(__fadd_rn(s[2], s[10]), __fadd_rn(s[6], s[14]));
    const float u3 = __fadd_rn(__fadd_rn(s[3], s[11]), __fadd_rn(s[7], s[15]));
    return __fadd_rn(__fadd_rn(u0, u2), __fadd_rn(u1, u3));
}

__global__ __launch_bounds__(256) void k_A(const float* __restrict__ z,
                                           float* __restrict__ A) {
    const int n = blockIdx.x * 256 + threadIdx.x;
    const float* zp = z + (size_t)(n >> 13) * (CDIM * THW) + (n & (THW - 1));
    const float b0 = pairwise128_sq(zp, THW);
    const float b1 = pairwise128_sq(zp + (size_t)128 * THW, THW);
    A[n] = __fadd_rn(b0, b1);
}

__global__ __launch_bounds__(256) void k_C(const float* __restrict__ w,
                                           float* __restrict__ Cq) {
    const int k = blockIdx.x * 256 + threadIdx.x;
    const float* wp = w + (size_t)k * CDIM;
    Cq[k] = __fadd_rn(pairwise128_sq(wp, 1), pairwise128_sq(wp + 128, 1));
}

__global__ __launch_bounds__(256) void k_split(const float* __restrict__ w,
                                               unsigned short* __restrict__ W1,
                                               unsigned short* __restrict__ W2) {
    const int i = blockIdx.x * 256 + threadIdx.x;
    float4 v = *reinterpret_cast<const float4*>(w + (size_t)i * 4);
    const float x[4] = {v.x, v.y, v.z, v.w};
    u16x4 h, lo;
#pragma unroll
    for (int q = 0; q < 4; ++q) {
        const unsigned short hh = bf16rn(x[q]);
        h[q] = hh;
        lo[q] = bf16rn(x[q] - bf16tof(hh));
    }
    *reinterpret_cast<u16x4*>(W1 + (size_t)i * 4) = h;
    *reinterpret_cast<u16x4*>(W2 + (size_t)i * 4) = lo;
}

// MFMA split-bf16 filter ranking sigma_k = Cq[k] - 2*dot_f (no A, no RN@256).
// np-winner satisfies sigma(k*) <= sigma(k) + 6.4e-5 (2 half-ulps of the two
// np RN steps at scale<512 + GEMM delta'); rows with top-2 sigma gap <= WSIG
// are flagged for np-exact resolve. dot_f numerics verified rounds 10/11.
__global__ __launch_bounds__(256, 2) void k_filter(
    const float* __restrict__ z,
    const unsigned short* __restrict__ W1, const unsigned short* __restrict__ W2,
    const float* __restrict__ Cq,
    float* __restrict__ idx_f, int* __restrict__ flag, int* __restrict__ cnt64)
{
    __shared__ unsigned short Z1t[64 * 256];  // 32 KB, [n][c] swizzled bf16 hi
    __shared__ unsigned short Z2t[64 * 256];  // 32 KB, lo
    __shared__ float wm1[4][64];
    __shared__ int   wi1[4][64];
    __shared__ float wm2[4][64];

    const int t = threadIdx.x;
    const int blk = blockIdx.x;
    const int b = (blk * 64) >> 13;
    const int s0 = (blk * 64) & (THW - 1);
    const float* zb = z + (size_t)b * (CDIM * THW) + s0;

    {   // stage + split z tile (coalesced reads, swizzled LDS writes)
        const int lane = t & 15;
        const int c0 = t >> 4;
#pragma unroll
        for (int it = 0; it < 16; ++it) {
            const int c = c0 + it * 16;
            float4 v = *reinterpret_cast<const float4*>(zb + (size_t)c * THW + lane * 4);
            const float vv[4] = {v.x, v.y, v.z, v.w};
#pragma unroll
            for (int q = 0; q < 4; ++q) {
                const int n = lane * 4 + q;
                const unsigned short h = bf16rn(vv[q]);
                const unsigned short l2 = bf16rn(vv[q] - bf16tof(h));
                const int off = n * 512 + ((c * 2) ^ ((n & 7) << 4));
                *(unsigned short*)((char*)Z1t + off) = h;
                *(unsigned short*)((char*)Z2t + off) = l2;
            }
        }
    }
    __syncthreads();

    const int l = t & 63;
    const int wv = t >> 6;
    const int l15 = l & 15;
    const int lg = l >> 4;
    const int stripe = wv * 2048;

    float b1r[4][4], b2r[4][4];
    int k1r[4][4];
#pragma unroll
    for (int rt = 0; rt < 4; ++rt)
#pragma unroll
        for (int i = 0; i < 4; ++i) {
            b1r[rt][i] = 3.0e38f; b2r[rt][i] = 3.0e38f; k1r[rt][i] = INT_MAX;
        }

    for (int st = 0; st < 32; ++st) {
        const int kb = stripe + st * 64;
        f32x4 acc[4][4];
#pragma unroll
        for (int rt = 0; rt < 4; ++rt)
#pragma unroll
            for (int ct = 0; ct < 4; ++ct)
                acc[rt][ct] = (f32x4){0.f, 0.f, 0.f, 0.f};

        float cqv[4];
#pragma unroll
        for (int ct = 0; ct < 4; ++ct) cqv[ct] = Cq[kb + ct * 16 + l15];

#pragma unroll
        for (int ks = 0; ks < 8; ++ks) {
            const int cb = ks * 32 + lg * 8;
            short8v a1[4], a2[4], bb1[4], bb2[4];
#pragma unroll
            for (int rt = 0; rt < 4; ++rt) {
                const int n = rt * 16 + l15;
                const int off = n * 512 + ((cb * 2) ^ ((n & 7) << 4));
                a1[rt] = *(const short8v*)((const char*)Z1t + off);
                a2[rt] = *(const short8v*)((const char*)Z2t + off);
            }
#pragma unroll
            for (int ct = 0; ct < 4; ++ct) {
                const size_t wo = (size_t)(kb + ct * 16 + l15) * CDIM + cb;
                bb1[ct] = *reinterpret_cast<const short8v*>(W1 + wo);
                bb2[ct] = *reinterpret_cast<const short8v*>(W2 + wo);
            }
#pragma unroll
            for (int rt = 0; rt < 4; ++rt)
#pragma unroll
                for (int ct = 0; ct < 4; ++ct) {
                    acc[rt][ct] = __builtin_amdgcn_mfma_f32_16x16x32_bf16(a1[rt], bb1[ct], acc[rt][ct], 0, 0, 0);
                    acc[rt][ct] = __builtin_amdgcn_mfma_f32_16x16x32_bf16(a1[rt], bb2[ct], acc[rt][ct], 0, 0, 0);
                    acc[rt][ct] = __builtin_amdgcn_mfma_f32_16x16x32_bf16(a2[rt], bb1[ct], acc[rt][ct], 0, 0, 0);
                }
        }

        // sigma = Cq - 2*dot (1 fma); per-lane top-2 per row; k ascending.
#pragma unroll
        for (int rt = 0; rt < 4; ++rt)
#pragma unroll
            for (int i = 0; i < 4; ++i) {
#pragma unroll
                for (int ct = 0; ct < 4; ++ct) {
                    const float sig = fmaf(-2.0f, acc[rt][ct][i], cqv[ct]);
                    const int kg = kb + ct * 16 + l15;
                    if (sig < b1r[rt][i]) {
                        b2r[rt][i] = b1r[rt][i]; b1r[rt][i] = sig; k1r[rt][i] = kg;
                    } else {
                        b2r[rt][i] = fminf(b2r[rt][i], sig);
                    }
                }
            }
    }

    // top-2 merge across the 16 l15-lanes of each lg group (ties -> lower k)
#pragma unroll
    for (int mm = 1; mm < 16; mm <<= 1) {
#pragma unroll
        for (int rt = 0; rt < 4; ++rt)
#pragma unroll
            for (int i = 0; i < 4; ++i) {
                const float ob = __shfl_xor(b1r[rt][i], mm, 64);
                const int oi = __shfl_xor(k1r[rt][i], mm, 64);
                const float ob2 = __shfl_xor(b2r[rt][i], mm, 64);
                if (ob < b1r[rt][i] || (ob == b1r[rt][i] && oi < k1r[rt][i])) {
                    b2r[rt][i] = fminf(b1r[rt][i], ob2);
                    b1r[rt][i] = ob; k1r[rt][i] = oi;
                } else {
                    b2r[rt][i] = fminf(b2r[rt][i], ob);
                }
            }
    }
    if (l15 == 0) {
#pragma unroll
        for (int rt = 0; rt < 4; ++rt)
#pragma unroll
            for (int i = 0; i < 4; ++i) {
                const int row = rt * 16 + lg * 4 + i;
                wm1[wv][row] = b1r[rt][i];
                wi1[wv][row] = k1r[rt][i];
                wm2[wv][row] = b2r[rt][i];
            }
    }
    __syncthreads();

    if (t < 64) {   // wave 0 exactly
        float m1 = 3.0e38f, m2 = 3.0e38f;
        int i1 = INT_MAX;
#pragma unroll
        for (int v = 0; v < 4; ++v) {
            const float a1 = wm1[v][t], a2 = wm2[v][t];
            const int ai = wi1[v][t];
            if (a1 < m1 || (a1 == m1 && ai < i1)) {
                m2 = fminf(m1, a2); m1 = a1; i1 = ai;
            } else {
                m2 = fminf(m2, a1);
            }
        }
        const int n = blk * 64 + t;
        idx_f[n] = (float)i1;
        const int flg = (m2 - m1 <= WSIG) ? 1 : 0;
        flag[n] = flg;
        const unsigned long long msk = __ballot(flg);
        if (t == 0) cnt64[blk] = (int)__popcll(msk);
    }
}

// Exclusive prefix over the 512 per-block counts (one block, LDS scan).
__global__ __launch_bounds__(512) void k_scan(const int* __restrict__ cnt64,
                                              int* __restrict__ off,
                                              int* __restrict__ nf) {
    __shared__ int sh[512];
    const int t = threadIdx.x;
    const int c = cnt64[t];
    sh[t] = c;
    __syncthreads();
    for (int o = 1; o < 512; o <<= 1) {
        const int v = (t >= o) ? sh[t - o] : 0;
        __syncthreads();
        sh[t] += v;
        __syncthreads();
    }
    off[t] = sh[t] - c;
    if (t == 511) nf[0] = sh[511];
}

// Order-preserving compaction of flagged rows (ballot prefix, no atomics).
__global__ __launch_bounds__(64) void k_scatter(const int* __restrict__ flag,
                                                const int* __restrict__ off,
                                                int* __restrict__ wlist) {
    const int t = threadIdx.x;
    const int n = blockIdx.x * 64 + t;
    const int flg = flag[n];
    const unsigned long long msk = __ballot(flg);
    const int pre = (int)__popcll(msk & ((1ull << t) - 1ull));
    if (flg) wlist[off[blockIdx.x] + pre] = n;
}

// Transpose w[k][c] -> wT[c][k] (into the dead W1/W2 region; runs post-filter).
__global__ __launch_bounds__(256) void k_T(const float* __restrict__ w,
                                           float* __restrict__ wT) {
    __shared__ float tile[64][65];
    const int t = threadIdx.x;
    const int kt = blockIdx.x >> 2;
    const int ct = blockIdx.x & 3;
    const int k0 = kt * 64, c0 = ct * 64;
    const int rg = t >> 4, cl = (t & 15) * 4;
#pragma unroll
    for (int i = 0; i < 4; ++i) {
        const int r = rg + i * 16;
        float4 v = *reinterpret_cast<const float4*>(w + (size_t)(k0 + r) * CDIM + c0 + cl);
        tile[r][cl] = v.x; tile[r][cl + 1] = v.y;
        tile[r][cl + 2] = v.z; tile[r][cl + 3] = v.w;
    }
    __syncthreads();
#pragma unroll
    for (int i = 0; i < 4; ++i) {
        const int cr = rg + i * 16;
        float4 o;
        o.x = tile[cl + 0][cr]; o.y = tile[cl + 1][cr];
        o.z = tile[cl + 2][cr]; o.w = tile[cl + 3][cr];
        *reinterpret_cast<float4*>(wT + (size_t)(c0 + cr) * KDIM + k0 + cl) = o;
    }
}

// np-exact resolve GEMM over compacted flagged rows (round-7-verified chain):
// 8 rows x 8 k per thread, single ascending-c fmaf chain, d = RN(RN(A-2M)+Cq),
// argmin ties -> lowest k.
#define PW(buf, p) { \
    const int pp_ = (p) < 4095 ? (p) : 4095; \
    const float* ap_ = wT + ((size_t)(pp_ & 255) << 13) + ((pp_ >> 8) << 9) + lane8; \
    buf[0] = *(const float4*)(ap_); \
    buf[1] = *(const float4*)(ap_ + 4); }

#define PZ(buf, p) { \
    const float* zp_ = &zt[(p) & 255][wv8]; \
    buf[0] = *(const float4*)(zp_); \
    buf[1] = *(const float4*)(zp_ + 4); }

#define COMP(wb_, zb_) { \
    const float wr_[8] = {wb_[0].x, wb_[0].y, wb_[0].z, wb_[0].w, \
                          wb_[1].x, wb_[1].y, wb_[1].z, wb_[1].w}; \
    const float zr_[8] = {zb_[0].x, zb_[0].y, zb_[0].z, zb_[0].w, \
                          zb_[1].x, zb_[1].y, zb_[1].z, zb_[1].w}; \
    _Pragma("unroll") \
    for (int r_ = 0; r_ < 8; ++r_) \
        _Pragma("unroll") \
        for (int j_ = 0; j_ < 8; ++j_) \
            acc[r_][j_] = fmaf(zr_[r_], wr_[j_], acc[r_][j_]); }

__global__ __launch_bounds__(256, 4) void k_resolve(
    const float* __restrict__ z, const float* __restrict__ wT,
    const float* __restrict__ A, const float* __restrict__ Cq,
    const int* __restrict__ nf_p, const int* __restrict__ wlist,
    float* __restrict__ idx_f)
{
    __shared__ float zt[CDIM][BNR];   // 32 KB gathered z tile
    __shared__ int rows[BNR];

    const int t = threadIdx.x;
    const int blk = blockIdx.x;
    const int nf = nf_p[0];
    const int base = blk * BNR;
    if (base >= nf) return;

    if (t < BNR) {
        const int g = base + t;
        rows[t] = wlist[g < nf ? g : base];   // pad slots duplicate a valid row
    }
    __syncthreads();

    {   // gathered z stage: thread t -> row j = t&31, c = (t>>5) + 8*cc
        const int j = t & 31;
        const int c0 = t >> 5;
        const int row = rows[j];
        const float* zp = z + (size_t)(row >> 13) * (CDIM * THW) + (row & (THW - 1));
#pragma unroll
        for (int cc = 0; cc < 32; ++cc) {
            const int c = c0 + cc * 8;
            zt[c][j] = zp[(size_t)c * THW];
        }
    }
    __syncthreads();

    const int lane8 = (t & 63) * 8;
    const int wv8 = (t >> 6) * 8;

    float Ar[8];
#pragma unroll
    for (int r = 0; r < 8; ++r) Ar[r] = A[rows[wv8 + r]];

    float best[8];
    int bidx[8];
#pragma unroll
    for (int r = 0; r < 8; ++r) { best[r] = 3.0e38f; bidx[r] = INT_MAX; }

    float4 wa[2], wb[2], za[2], zb4[2];
    PW(wa, 0); PZ(za, 0);

    for (int kt = 0; kt < 16; ++kt) {
        float acc[8][8];
#pragma unroll
        for (int r = 0; r < 8; ++r)
#pragma unroll
            for (int j = 0; j < 8; ++j) acc[r][j] = 0.f;

        const int pbase = kt * 256;
        for (int c2 = 0; c2 < 256; c2 += 2) {
            PW(wb, pbase + c2 + 1); PZ(zb4, pbase + c2 + 1);
            COMP(wa, za);
            PW(wa, pbase + c2 + 2); PZ(za, pbase + c2 + 2);
            COMP(wb, zb4);
        }

        const float4 cq0 = *reinterpret_cast<const float4*>(Cq + kt * 512 + lane8);
        const float4 cq1 = *reinterpret_cast<const float4*>(Cq + kt * 512 + lane8 + 4);
        const float cv[8] = {cq0.x, cq0.y, cq0.z, cq0.w, cq1.x, cq1.y, cq1.z, cq1.w};
#pragma unroll
        for (int j = 0; j < 8; ++j) {
            const int kg = kt * 512 + lane8 + j;
#pragma unroll
            for (int r = 0; r < 8; ++r) {
                const float dd = __fadd_rn(__fadd_rn(Ar[r], -2.0f * acc[r][j]), cv[j]);
                if (dd < best[r]) { best[r] = dd; bidx[r] = kg; }
            }
        }
    }

#pragma unroll
    for (int m = 1; m < 64; m <<= 1) {
#pragma unroll
        for (int r = 0; r < 8; ++r) {
            const float od = __shfl_xor(best[r], m, 64);
            const int oi = __shfl_xor(bidx[r], m, 64);
            if (od < best[r] || (od == best[r] && oi < bidx[r])) {
                best[r] = od; bidx[r] = oi;
            }
        }
    }
    if ((t & 63) == 0) {
#pragma unroll
        for (int r = 0; r < 8; ++r) {
            const int slot = wv8 + r;
            if (base + slot < nf) idx_f[rows[slot]] = (float)bidx[r];
        }
    }
}

// Gather z_q = w[idx], transpose to [B,C,T,H,W], accumulate sum((z_q - z)^2).
__global__ __launch_bounds__(256, 2) void k_out(
    const float* __restrict__ w, const float* __restrict__ z,
    const float* __restrict__ idx_f, float* __restrict__ out0,
    float* __restrict__ partial)
{
    __shared__ float q[CDIM][BNQ + 1];
    __shared__ int si[BNQ];
    __shared__ float red[256];

    const int t = threadIdx.x;
    const int blk = blockIdx.x;
    const int n0 = blk * BNQ;
    const int b = n0 >> 13;
    const int s0 = n0 & (THW - 1);

    if (t < BNQ) si[t] = (int)idx_f[n0 + t];
    __syncthreads();

    {
        const int c = t;
#pragma unroll 4
        for (int i = 0; i < BNQ; ++i)
            q[c][i] = w[(size_t)si[i] * CDIM + c];
    }
    __syncthreads();

    const int sl = t & 63;
    const int cb = t >> 6;
    float lacc = 0.f;
    const size_t base = (size_t)b * (CDIM * THW) + s0 + sl;
#pragma unroll 4
    for (int j = 0; j < 64; ++j) {
        const int c = cb * 64 + j;
        const float qv = q[c][sl];
        const size_t a = base + (size_t)c * THW;
        const float zv = z[a];
        out0[a] = qv;
        const float d = qv - zv;
        lacc = fmaf(d, d, lacc);
    }
    red[t] = lacc;
    __syncthreads();
    for (int mm = 128; mm > 0; mm >>= 1) {
        if (t < mm) red[t] += red[t + mm];
        __syncthreads();
    }
    if (t == 0) partial[blk] = red[0];
}

__global__ __launch_bounds__(256) void k_loss(const float* __restrict__ partial,
                                              float* __restrict__ out_loss) {
    __shared__ double red[256];
    const int t = threadIdx.x;
    double a = 0.0;
    for (int i = t; i < NROWS / BNQ; i += 256) a += (double)partial[i];
    red[t] = a;
    __syncthreads();
    for (int mm = 128; mm > 0; mm >>= 1) {
        if (t < mm) red[t] += red[t + mm];
        __syncthreads();
    }
    if (t == 0) out_loss[0] = (float)(1.25 * red[0] / 8388608.0);
}

extern "C" void kernel_launch(void* const* d_in, const int* in_sizes, int n_in,
                              void* d_out, int out_size, void* d_ws, size_t ws_size,
                              hipStream_t stream) {
    const float* z = (const float*)d_in[0];
    const float* w = (const float*)d_in[1];
    float* out = (float*)d_out;

    char* ws = (char*)d_ws;
    unsigned short* W1 = (unsigned short*)ws;                // 4 MB
    unsigned short* W2 = (unsigned short*)(ws + 4194304);    // 4 MB
    float* wT = (float*)ws;                                  // reuse after filter
    float* A = (float*)(ws + 8388608);
    float* Cq = (float*)(ws + 8519680);
    int* flag = (int*)(ws + 8552448);
    int* cnt64 = (int*)(ws + 8683520);
    int* off = (int*)(ws + 8685568);
    int* nf = (int*)(ws + 8687616);
    int* wlist = (int*)(ws + 8687680);
    float* partial = (float*)(ws + 8818752);

    float* out_zq = out;                 // [B,C,T,H,W] = 8388608
    float* out_loss = out + 8388608;     // scalar
    float* out_idx = out + 8388609;      // [B,T,H,W] = 32768, as float

    k_split<<<KDIM * CDIM / 4 / 256, 256, 0, stream>>>(w, W1, W2);
    k_A<<<NROWS / 256, 256, 0, stream>>>(z, A);
    k_C<<<KDIM / 256, 256, 0, stream>>>(w, Cq);
    k_filter<<<NROWS / 64, 256, 0, stream>>>(z, W1, W2, Cq, out_idx, flag, cnt64);
    k_scan<<<1, 512, 0, stream>>>(cnt64, off, nf);
    k_scatter<<<NROWS / 64, 64, 0, stream>>>(flag, off, wlist);
    k_T<<<512, 256, 0, stream>>>(w, wT);
    k_resolve<<<NROWS / BNR, 256, 0, stream>>>(z, wT, A, Cq, nf, wlist, out_idx);
    k_out<<<NROWS / BNQ, 256, 0, stream>>>(w, z, out_idx, out_zq, partial);
    k_loss<<<1, 256, 0, stream>>>(partial, out_loss);
}